// Round 6
// baseline (514.927 us; speedup 1.0000x reference)
//
#include <hip/hip_runtime.h>

#define NPB  8      // dense points per block (fused kernel)
#define KNN  16     // neighbors
#define CIN  128
#define CF   160    // Cin + PE
#define MM   16     // weightnet out channels
#define PEC  32     // positional encoding channels
#define COUT 128
#define KDIM 2560   // CF * MM
#define AROW 2568   // padded apack row (shorts): rotates banks for MFMA reads
#define WTR  20     // padded wts row stride (floats): 2-way banks = free
#define LEPS 1e-5f

typedef __bf16 bf16x8 __attribute__((ext_vector_type(8)));
typedef float  f32x4  __attribute__((ext_vector_type(4)));
union U16x8 { uint4 u4; bf16x8 b; unsigned short us[8]; };

// LDS weight-bank offsets (floats) -- overlaid on apack_s during nets phase
#define SW_PE_W0   0
#define SW_PE_B0   96
#define SW_PE_G0   128
#define SW_PE_BE0  160
#define SW_PE_W1   192
#define SW_PE_B1   1216
#define SW_PE_G1   1248
#define SW_PE_BE1  1280
#define SW_WN_W0   1312
#define SW_WN_B0   1360
#define SW_WN_G0   1376
#define SW_WN_BE0  1392
#define SW_WN_W1   1408
#define SW_WN_B1   1664
#define SW_WN_G1   1680
#define SW_WN_BE1  1696
#define SW_WN_W2   1712
#define SW_WN_B2   1968
#define SW_WN_G2   1984
#define SW_WN_BE2  2000
#define SW_TOTAL   2016

__device__ __forceinline__ float bf2f(unsigned short b){
  union { unsigned int u; float f; } x; x.u = ((unsigned int)b) << 16; return x.f;
}
__device__ __forceinline__ unsigned short f2bf(float f){
  union { float f; unsigned int u; } x; x.f = f;
  unsigned int r = (x.u + 0x7fffu + ((x.u >> 16) & 1u)) >> 16;
  return (unsigned short)r;
}
__device__ __forceinline__ float rsum16(float v){
  v += __shfl_xor(v, 8, 16);
  v += __shfl_xor(v, 4, 16);
  v += __shfl_xor(v, 2, 16);
  v += __shfl_xor(v, 1, 16);
  return v;
}
__device__ __forceinline__ float rsum32(float v){
  v += __shfl_xor(v, 16, 32);
  v += __shfl_xor(v, 8, 32);
  v += __shfl_xor(v, 4, 32);
  v += __shfl_xor(v, 2, 32);
  v += __shfl_xor(v, 1, 32);
  return v;
}
__device__ __forceinline__ float lrelu(float v){ return v >= 0.f ? v : 0.1f * v; }

template<int N>
__device__ __forceinline__ void ln_inlane(float* v, const float* g, const float* be, bool act){
  float mu = 0.f;
#pragma unroll
  for (int i = 0; i < N; ++i) mu += v[i];
  mu *= (1.f / N);
  float var = 0.f;
#pragma unroll
  for (int i = 0; i < N; ++i) { float d = v[i] - mu; var += d * d; }
  const float rs = rsqrtf(var * (1.f / N) + LEPS);
#pragma unroll
  for (int i = 0; i < N; ++i) {
    float y = (v[i] - mu) * rs * g[i] + be[i];
    v[i] = act ? lrelu(y) : y;
  }
}

// ============================================================================
// Kernel P: pack lin_w (f32 [2560][128]) -> bf16 B-fragment layout for the
// permuted k-index i' = chunk*128 + m*8 + j  (c = chunk*8 + j, src row c*16+m).
// Fragment (s, tt, lane, j): i' = s*32 + (lane>>4)*8 + j, n = tt*16 + (lane&15)
// stored at wpack[((s*8 + tt)*64 + lane)*8 + j].
// ============================================================================
__global__ __launch_bounds__(256)
void pct_pack_w(const float* __restrict__ lin_w, unsigned short* __restrict__ wpack)
{
  const int u    = blockIdx.x * 256 + threadIdx.x;   // 0..40959
  const int lane = u & 63;
  const int tt   = (u >> 6) & 7;
  const int s    = u >> 9;
  const int ipb  = s * 32 + ((lane >> 4) * 8);
  const int nn   = tt * 16 + (lane & 15);
  unsigned short v[8];
#pragma unroll
  for (int j = 0; j < 8; ++j) {
    const int ip    = ipb + j;
    const int chunk = ip >> 7;
    const int rem   = ip & 127;
    const int m     = rem >> 3;
    const int jc    = rem & 7;
    const int srow  = (chunk * 8 + jc) * MM + m;    // lin_w row = c*16 + m
    v[j] = f2bf(lin_w[(long)srow * COUT + nn]);
  }
  *(uint4*)(wpack + (long)u * 8) = *(uint4*)v;
}

// ============================================================================
// Kernel F: fully fused nets + einsum(->LDS) + MFMA GEMM + LN epilogue.
// 256 threads, 8 points/block, 5000 blocks. No apack round-trip.
// ============================================================================
__global__ __launch_bounds__(256)
void pct_fused_mfma(
    const float* __restrict__ sparse_xyz,
    const float* __restrict__ sparse_feats,
    const int* __restrict__ nei_inds,
    const float* __restrict__ dense_xyz,
    const float* __restrict__ dense_feats,
    const float* __restrict__ pe_w0, const float* __restrict__ pe_b0,
    const float* __restrict__ pe_g0, const float* __restrict__ pe_be0,
    const float* __restrict__ pe_w1, const float* __restrict__ pe_b1,
    const float* __restrict__ pe_g1, const float* __restrict__ pe_be1,
    const float* __restrict__ wn_w0, const float* __restrict__ wn_b0,
    const float* __restrict__ wn_g0, const float* __restrict__ wn_be0,
    const float* __restrict__ wn_w1, const float* __restrict__ wn_b1,
    const float* __restrict__ wn_g1, const float* __restrict__ wn_be1,
    const float* __restrict__ wn_w2, const float* __restrict__ wn_b2,
    const float* __restrict__ wn_g2, const float* __restrict__ wn_be2,
    const unsigned short* __restrict__ wpack,
    const float* __restrict__ lin_b, const float* __restrict__ lin_g,
    const float* __restrict__ lin_be,
    float* __restrict__ out)
{
  // 41088 + 8192 + 10240 = 59520 B -> 2 blocks/CU
  __shared__ __align__(16) unsigned short apack_s[NPB * AROW];     // A-tile (bf16); first 8064 B double as sw
  __shared__ __align__(16) unsigned short pe_s[NPB * KNN * PEC];   // pe values; doubles as out_s in epilogue
  __shared__ __align__(16) float wts_s[NPB * MM * WTR];            // wts[p][m][k], padded stride

  float* sw    = (float*)apack_s;   // overlay (nets phase only)
  float* out_s = (float*)pe_s;      // overlay (epilogue only), row stride 132

  const int t     = threadIdx.x;
  const int nbase = blockIdx.x * NPB;

  // ---- stage small-net weights into LDS ----
  for (int i = t; i < 96;   i += 256) sw[SW_PE_W0 + i] = pe_w0[i];
  for (int i = t; i < 32;   i += 256) {
    sw[SW_PE_B0 + i] = pe_b0[i];  sw[SW_PE_G0 + i] = pe_g0[i];  sw[SW_PE_BE0 + i] = pe_be0[i];
    sw[SW_PE_B1 + i] = pe_b1[i];  sw[SW_PE_G1 + i] = pe_g1[i];  sw[SW_PE_BE1 + i] = pe_be1[i];
  }
  for (int i = t; i < 1024; i += 256) sw[SW_PE_W1 + i] = pe_w1[i];
  for (int i = t; i < 48;   i += 256) sw[SW_WN_W0 + i] = wn_w0[i];
  for (int i = t; i < 16;   i += 256) {
    sw[SW_WN_B0 + i] = wn_b0[i];  sw[SW_WN_G0 + i] = wn_g0[i];  sw[SW_WN_BE0 + i] = wn_be0[i];
    sw[SW_WN_B1 + i] = wn_b1[i];  sw[SW_WN_G1 + i] = wn_g1[i];  sw[SW_WN_BE1 + i] = wn_be1[i];
    sw[SW_WN_B2 + i] = wn_b2[i];  sw[SW_WN_G2 + i] = wn_g2[i];  sw[SW_WN_BE2 + i] = wn_be2[i];
  }
  for (int i = t; i < 256;  i += 256) { sw[SW_WN_W1 + i] = wn_w1[i]; sw[SW_WN_W2 + i] = wn_w2[i]; }
  __syncthreads();

  // ---- nets phase: thread t<128 handles pair (p = t>>4, k = t&15) ----
  if (t < 128) {
    const int p  = t >> 4;
    const int kk = t & 15;
    const int n  = nbase + p;
    const int idx = nei_inds[n * KNN + kk];
    const float x0 = sparse_xyz[idx*3+0] - dense_xyz[n*3+0];
    const float x1 = sparse_xyz[idx*3+1] - dense_xyz[n*3+1];
    const float x2 = sparse_xyz[idx*3+2] - dense_xyz[n*3+2];

    // pe layer0 (3->32) + LN + act
    float h[32];
#pragma unroll
    for (int c = 0; c < 32; ++c)
      h[c] = x0*sw[SW_PE_W0+c] + x1*sw[SW_PE_W0+32+c] + x2*sw[SW_PE_W0+64+c] + sw[SW_PE_B0+c];
    ln_inlane<32>(h, &sw[SW_PE_G0], &sw[SW_PE_BE0], true);

    // pe layer1 (32->32) + LN (no act)
    float z[32];
#pragma unroll
    for (int c = 0; c < 32; ++c) z[c] = sw[SW_PE_B1 + c];
#pragma unroll 4
    for (int j = 0; j < 32; ++j) {
      const float hj = h[j];
#pragma unroll
      for (int c = 0; c < 32; ++c) z[c] += hj * sw[SW_PE_W1 + j*32 + c];
    }
    ln_inlane<32>(z, &sw[SW_PE_G1], &sw[SW_PE_BE1], false);
#pragma unroll
    for (int c = 0; c < 32; ++c) pe_s[(p*KNN + kk)*PEC + c] = f2bf(z[c]);

    // wn layer0 (3->16) + LN + act
    float w[16];
#pragma unroll
    for (int m = 0; m < 16; ++m)
      w[m] = x0*sw[SW_WN_W0+m] + x1*sw[SW_WN_W0+16+m] + x2*sw[SW_WN_W0+32+m] + sw[SW_WN_B0+m];
    ln_inlane<16>(w, &sw[SW_WN_G0], &sw[SW_WN_BE0], true);

    // wn layer1 (16->16) + LN + act
    float z2[16];
#pragma unroll
    for (int m = 0; m < 16; ++m) z2[m] = sw[SW_WN_B1 + m];
#pragma unroll 4
    for (int j = 0; j < 16; ++j) {
      const float wj = w[j];
#pragma unroll
      for (int m = 0; m < 16; ++m) z2[m] += wj * sw[SW_WN_W1 + j*16 + m];
    }
    ln_inlane<16>(z2, &sw[SW_WN_G1], &sw[SW_WN_BE1], true);

    // wn layer2 (16->16) + LN (no act)
#pragma unroll
    for (int m = 0; m < 16; ++m) w[m] = sw[SW_WN_B2 + m];
#pragma unroll 4
    for (int j = 0; j < 16; ++j) {
      const float wj = z2[j];
#pragma unroll
      for (int m = 0; m < 16; ++m) w[m] += wj * sw[SW_WN_W2 + j*16 + m];
    }
    ln_inlane<16>(w, &sw[SW_WN_G2], &sw[SW_WN_BE2], false);
    // wts_s[p][m][k], padded stride WTR
#pragma unroll
    for (int m = 0; m < 16; ++m) wts_s[p*(MM*WTR) + m*WTR + kk] = w[m];
  }
  __syncthreads();  // nets done; sw region free for apack writes

  // ---- einsum phase: thread = (chunk = t>>4 in 0..15, m = t&15) ----
  {
    const int chunk = t >> 4;
    const int m     = t & 15;

#pragma unroll 1
    for (int pp = 0; pp < NPB; ++pp) {
      const int* nidx = nei_inds + (long)(nbase + pp) * KNN;
      int idxs[KNN];
#pragma unroll
      for (int k = 0; k < KNN; ++k) idxs[k] = nidx[k];

      float wkv[KNN];
      {
        const float* wr = &wts_s[pp*(MM*WTR) + m*WTR];
#pragma unroll
        for (int q = 0; q < 4; ++q) {
          const float4 wv = *(const float4*)(wr + q*4);
          wkv[q*4+0] = wv.x; wkv[q*4+1] = wv.y; wkv[q*4+2] = wv.z; wkv[q*4+3] = wv.w;
        }
      }

      float acc[8];
#pragma unroll
      for (int j = 0; j < 8; ++j) acc[j] = 0.f;
#pragma unroll
      for (int k = 0; k < KNN; ++k) {
        const float* src = sparse_feats + (long)idxs[k] * CIN + chunk*8;
        const float4 a = *(const float4*)(src);
        const float4 b = *(const float4*)(src + 4);
        const float wv = wkv[k];
        acc[0] += a.x*wv; acc[1] += a.y*wv; acc[2] += a.z*wv; acc[3] += a.w*wv;
        acc[4] += b.x*wv; acc[5] += b.y*wv; acc[6] += b.z*wv; acc[7] += b.w*wv;
      }
      unsigned short ob[8];
#pragma unroll
      for (int j = 0; j < 8; ++j) ob[j] = f2bf(acc[j]);
      *(uint4*)(apack_s + pp*AROW + chunk*128 + m*8) = *(uint4*)ob;

      // pe chunks (16..19): wave 0 only (uniform branch, cheap LDS source)
      if (t < 64) {
        float acc2[8];
#pragma unroll
        for (int j = 0; j < 8; ++j) acc2[j] = 0.f;
#pragma unroll
        for (int k = 0; k < KNN; ++k) {
          U16x8 f; f.u4 = *(const uint4*)(&pe_s[(pp*KNN + k)*PEC + chunk*8]);
          const float wv = wkv[k];
#pragma unroll
          for (int j = 0; j < 8; ++j) acc2[j] += bf2f(f.us[j]) * wv;
        }
        unsigned short ob2[8];
#pragma unroll
        for (int j = 0; j < 8; ++j) ob2[j] = f2bf(acc2[j]);
        *(uint4*)(apack_s + pp*AROW + (16 + chunk)*128 + m*8) = *(uint4*)ob2;
      }
    }
  }
  __syncthreads();  // A-tile ready (pe_s no longer needed)

  // ---- GEMM phase: 4 waves x 2 n-tiles; A from LDS, B from L2 wpack ----
  {
    const int lane = t & 63;
    const int wave = t >> 6;
    const unsigned short* ap  = apack_s + (lane & 7) * AROW + ((lane >> 4) * 8);
    const unsigned short* wp0 = wpack + ((long)(wave*2) * 64 + lane) * 8;

    f32x4 c0 = {0.f,0.f,0.f,0.f}, c1 = {0.f,0.f,0.f,0.f};
    U16x8 a, b0, b1;
    a.u4  = *(const uint4*)(ap);
    b0.u4 = *(const uint4*)(wp0);
    b1.u4 = *(const uint4*)(wp0 + 512);

#pragma unroll 4
    for (int s = 0; s < 80; ++s) {
      U16x8 na, nb0, nb1;
      if (s + 1 < 80) {
        na.u4  = *(const uint4*)(ap + (s+1)*32);
        nb0.u4 = *(const uint4*)(wp0 + (long)(s+1)*4096);
        nb1.u4 = *(const uint4*)(wp0 + (long)(s+1)*4096 + 512);
      }
      c0 = __builtin_amdgcn_mfma_f32_16x16x32_bf16(a.b, b0.b, c0, 0, 0, 0);
      c1 = __builtin_amdgcn_mfma_f32_16x16x32_bf16(a.b, b1.b, c1, 0, 0, 0);
      a = na; b0 = nb0; b1 = nb1;
    }

    // scatter valid rows (0..7 = quads 0,1); rows 8..15 are duplicates
    const int quad = lane >> 4;
    if (quad < 2) {
      const int col = wave*32 + (lane & 15);
#pragma unroll
      for (int r = 0; r < 4; ++r) {
        out_s[(quad*4 + r)*132 + col     ] = c0[r];
        out_s[(quad*4 + r)*132 + col + 16] = c1[r];
      }
    }
  }
  __syncthreads();

  // ---- epilogue: 32 threads/point, bias + LN + LeakyReLU + residual ----
  {
    const int p = t >> 5, l = t & 31;
    const int n = nbase + p;
    float v[4];
#pragma unroll
    for (int j = 0; j < 4; ++j) {
      const int o = l + (j << 5);
      v[j] = out_s[p*132 + o] + lin_b[o];
    }
    float mu = rsum32(v[0] + v[1] + v[2] + v[3]) * (1.f/128.f);
    float q = 0.f;
#pragma unroll
    for (int j = 0; j < 4; ++j) { float d = v[j] - mu; q += d*d; }
    float rs = rsqrtf(rsum32(q) * (1.f/128.f) + LEPS);
#pragma unroll
    for (int j = 0; j < 4; ++j) {
      const int o = l + (j << 5);
      float y = (v[j] - mu) * rs * lin_g[o] + lin_be[o];
      y = lrelu(y);
      y += dense_feats[(long)n*COUT + o];
      out[(long)n*COUT + o] = y;
    }
  }
}

// ============================================================================
// Fallback: round-2 fully-fused VALU kernel (used if ws_size is too small)
// ============================================================================
__global__ __launch_bounds__(256)
void pct_fused(
    const float* __restrict__ sparse_xyz,
    const float* __restrict__ sparse_feats,
    const int* __restrict__ nei_inds,
    const float* __restrict__ dense_xyz,
    const float* __restrict__ dense_feats,
    const float* __restrict__ pe_w0, const float* __restrict__ pe_b0,
    const float* __restrict__ pe_g0, const float* __restrict__ pe_be0,
    const float* __restrict__ pe_w1, const float* __restrict__ pe_b1,
    const float* __restrict__ pe_g1, const float* __restrict__ pe_be1,
    const float* __restrict__ wn_w0, const float* __restrict__ wn_b0,
    const float* __restrict__ wn_g0, const float* __restrict__ wn_be0,
    const float* __restrict__ wn_w1, const float* __restrict__ wn_b1,
    const float* __restrict__ wn_g1, const float* __restrict__ wn_be1,
    const float* __restrict__ wn_w2, const float* __restrict__ wn_b2,
    const float* __restrict__ wn_g2, const float* __restrict__ wn_be2,
    const float* __restrict__ lin_w, const float* __restrict__ lin_b,
    const float* __restrict__ lin_g, const float* __restrict__ lin_be,
    float* __restrict__ out)
{
  __shared__ __align__(16) unsigned short feat_s[KNN][CF];
  __shared__ float wts_f[KNN][MM];
  __shared__ float loc_s[KNN][3];
  __shared__ int   nei_s[KNN];
  __shared__ __align__(16) unsigned short out_tile[CF*MM][8];

  const int t  = threadIdx.x;
  const int n0 = blockIdx.x * 8;
  const int k  = t >> 4;
  const int l  = t & 15;

#pragma unroll 1
  for (int p = 0; p < 8; ++p) {
    const int n = n0 + p;
    if (t < KNN) {
      int idx = nei_inds[n*KNN + t];
      nei_s[t] = idx;
      loc_s[t][0] = sparse_xyz[idx*3+0] - dense_xyz[n*3+0];
      loc_s[t][1] = sparse_xyz[idx*3+1] - dense_xyz[n*3+1];
      loc_s[t][2] = sparse_xyz[idx*3+2] - dense_xyz[n*3+2];
    }
    __syncthreads();
    {
      const int gk = t >> 4;
      const int c8 = (t & 15) * 8;
      const float* src = sparse_feats + (long)nei_s[gk]*CIN + c8;
      const float4 va = *(const float4*)(src);
      const float4 vb = *(const float4*)(src + 4);
      unsigned short* dst = &feat_s[gk][c8];
      dst[0] = f2bf(va.x); dst[1] = f2bf(va.y); dst[2] = f2bf(va.z); dst[3] = f2bf(va.w);
      dst[4] = f2bf(vb.x); dst[5] = f2bf(vb.y); dst[6] = f2bf(vb.z); dst[7] = f2bf(vb.w);
    }
    const float x0 = loc_s[k][0], x1 = loc_s[k][1], x2 = loc_s[k][2];
    const int c0 = l, c1 = l + 16;
    float ha = x0*pe_w0[0*PEC+c0] + x1*pe_w0[1*PEC+c0] + x2*pe_w0[2*PEC+c0] + pe_b0[c0];
    float hb = x0*pe_w0[0*PEC+c1] + x1*pe_w0[1*PEC+c1] + x2*pe_w0[2*PEC+c1] + pe_b0[c1];
    {
      float mu = rsum16(ha + hb) * (1.f/32.f);
      float da = ha - mu, db = hb - mu;
      float q  = rsum16(da*da + db*db);
      float rs = rsqrtf(q*(1.f/32.f) + LEPS);
      ha = lrelu(da*rs*pe_g0[c0] + pe_be0[c0]);
      hb = lrelu(db*rs*pe_g0[c1] + pe_be0[c1]);
    }
    float za = pe_b1[c0], zb = pe_b1[c1];
#pragma unroll
    for (int j = 0; j < 16; ++j) {
      float va = __shfl(ha, j, 16);
      float vb = __shfl(hb, j, 16);
      za += va * pe_w1[j*PEC + c0] + vb * pe_w1[(j+16)*PEC + c0];
      zb += va * pe_w1[j*PEC + c1] + vb * pe_w1[(j+16)*PEC + c1];
    }
    {
      float mu = rsum16(za + zb) * (1.f/32.f);
      float da = za - mu, db = zb - mu;
      float q  = rsum16(da*da + db*db);
      float rs = rsqrtf(q*(1.f/32.f) + LEPS);
      feat_s[k][CIN + c0] = f2bf(da*rs*pe_g1[c0] + pe_be1[c0]);
      feat_s[k][CIN + c1] = f2bf(db*rs*pe_g1[c1] + pe_be1[c1]);
    }
    float w0v = x0*wn_w0[0*MM+l] + x1*wn_w0[1*MM+l] + x2*wn_w0[2*MM+l] + wn_b0[l];
    {
      float mu = rsum16(w0v) * (1.f/16.f);
      float d  = w0v - mu;
      float rs = rsqrtf(rsum16(d*d)*(1.f/16.f) + LEPS);
      w0v = lrelu(d*rs*wn_g0[l] + wn_be0[l]);
    }
    float w1v = wn_b1[l];
#pragma unroll
    for (int j = 0; j < 16; ++j)
      w1v += __shfl(w0v, j, 16) * wn_w1[j*MM + l];
    {
      float mu = rsum16(w1v) * (1.f/16.f);
      float d  = w1v - mu;
      float rs = rsqrtf(rsum16(d*d)*(1.f/16.f) + LEPS);
      w1v = lrelu(d*rs*wn_g1[l] + wn_be1[l]);
    }
    float w2v = wn_b2[l];
#pragma unroll
    for (int j = 0; j < 16; ++j)
      w2v += __shfl(w1v, j, 16) * wn_w2[j*MM + l];
    {
      float mu = rsum16(w2v) * (1.f/16.f);
      float d  = w2v - mu;
      float rs = rsqrtf(rsum16(d*d)*(1.f/16.f) + LEPS);
      w2v = d*rs*wn_g2[l] + wn_be2[l];
    }
    wts_f[k][l] = w2v;
    __syncthreads();
    {
      const int m = t & 15;
      const int g = t >> 4;
      float wv[KNN];
#pragma unroll
      for (int kk = 0; kk < KNN; ++kk) wv[kk] = wts_f[kk][m];
#pragma unroll
      for (int j = 0; j < 10; ++j) {
        const int c = g*10 + j;
        float acc = 0.f;
#pragma unroll
        for (int kk = 0; kk < KNN; ++kk)
          acc += bf2f(feat_s[kk][c]) * wv[kk];
        out_tile[c*MM + m][p] = f2bf(acc);
      }
    }
    __syncthreads();
  }
  {
    const int h  = t >> 6;
    const int o0 = (t & 63) * 2;
    float acc0[8], acc1[8];
#pragma unroll
    for (int p = 0; p < 8; ++p) { acc0[p] = 0.f; acc1[p] = 0.f; }
    const int i0 = h * 640;
    for (int i = i0; i < i0 + 640; ++i) {
      const float2 wv = *(const float2*)(lin_w + (long)i*COUT + o0);
      const float wa = wv.x;
      const float wc = wv.y;
      const uint4 r = *(const uint4*)(&out_tile[i][0]);
      const float f0 = bf2f((unsigned short)(r.x & 0xffffu));
      const float f1 = bf2f((unsigned short)(r.x >> 16));
      const float g2 = bf2f((unsigned short)(r.y & 0xffffu));
      const float g3 = bf2f((unsigned short)(r.y >> 16));
      const float g4 = bf2f((unsigned short)(r.z & 0xffffu));
      const float g5 = bf2f((unsigned short)(r.z >> 16));
      const float g6 = bf2f((unsigned short)(r.w & 0xffffu));
      const float g7 = bf2f((unsigned short)(r.w >> 16));
      acc0[0] += f0*wa; acc1[0] += f0*wc;
      acc0[1] += f1*wa; acc1[1] += f1*wc;
      acc0[2] += g2*wa; acc1[2] += g2*wc;
      acc0[3] += g3*wa; acc1[3] += g3*wc;
      acc0[4] += g4*wa; acc1[4] += g4*wc;
      acc0[5] += g5*wa; acc1[5] += g5*wc;
      acc0[6] += g6*wa; acc1[6] += g6*wc;
      acc0[7] += g7*wa; acc1[7] += g7*wc;
    }
    __syncthreads();
    float* red = (float*)&out_tile[0][0];
#pragma unroll
    for (int p = 0; p < 8; ++p) {
      red[((h*8 + p) << 7) + o0    ] = acc0[p];
      red[((h*8 + p) << 7) + o0 + 1] = acc1[p];
    }
    __syncthreads();
    const int p2 = t >> 5, l2 = t & 31;
    const int n  = n0 + p2;
    float v[4];
#pragma unroll
    for (int j = 0; j < 4; ++j) {
      const int o = l2 + (j << 5);
      float sv = red[((0*8 + p2) << 7) + o] + red[((1*8 + p2) << 7) + o]
               + red[((2*8 + p2) << 7) + o] + red[((3*8 + p2) << 7) + o];
      v[j] = sv + lin_b[o];
    }
    float mu = rsum32(v[0] + v[1] + v[2] + v[3]) * (1.f/128.f);
    float q = 0.f;
#pragma unroll
    for (int j = 0; j < 4; ++j) { float d = v[j] - mu; q += d*d; }
    float rs = rsqrtf(rsum32(q) * (1.f/128.f) + LEPS);
#pragma unroll
    for (int j = 0; j < 4; ++j) {
      const int o = l2 + (j << 5);
      float y = (v[j] - mu) * rs * lin_g[o] + lin_be[o];
      y = lrelu(y);
      y += dense_feats[n*COUT + o];
      out[n*COUT + o] = y;
    }
  }
}

extern "C" void kernel_launch(void* const* d_in, const int* in_sizes, int n_in,
                              void* d_out, int out_size, void* d_ws, size_t ws_size,
                              hipStream_t stream) {
  const int Nd = in_sizes[2] / KNN;   // 40000
  const size_t w_bytes = (size_t)KDIM * COUT * 2;   // 655 KB
  const bool use_mfma = (ws_size >= w_bytes) && (Nd % NPB == 0);

  if (use_mfma) {
    unsigned short* wpack = (unsigned short*)d_ws;

    pct_pack_w<<<dim3((KDIM/32)*8*64/256), dim3(256), 0, stream>>>(
      (const float*)d_in[27], wpack);

    pct_fused_mfma<<<dim3(Nd / NPB), dim3(256), 0, stream>>>(
      (const float*)d_in[0],  (const float*)d_in[1],  (const int*)d_in[2],
      (const float*)d_in[4],  (const float*)d_in[6],
      (const float*)d_in[7],  (const float*)d_in[8],  (const float*)d_in[9],  (const float*)d_in[10],
      (const float*)d_in[11], (const float*)d_in[12], (const float*)d_in[13], (const float*)d_in[14],
      (const float*)d_in[15], (const float*)d_in[16], (const float*)d_in[17], (const float*)d_in[18],
      (const float*)d_in[19], (const float*)d_in[20], (const float*)d_in[21], (const float*)d_in[22],
      (const float*)d_in[23], (const float*)d_in[24], (const float*)d_in[25], (const float*)d_in[26],
      wpack,
      (const float*)d_in[28], (const float*)d_in[29], (const float*)d_in[30],
      (float*)d_out);
  } else {
    pct_fused<<<dim3(Nd / 8), dim3(256), 0, stream>>>(
      (const float*)d_in[0],  (const float*)d_in[1],  (const int*)d_in[2],
      (const float*)d_in[4],  (const float*)d_in[6],
      (const float*)d_in[7],  (const float*)d_in[8],  (const float*)d_in[9],  (const float*)d_in[10],
      (const float*)d_in[11], (const float*)d_in[12], (const float*)d_in[13], (const float*)d_in[14],
      (const float*)d_in[15], (const float*)d_in[16], (const float*)d_in[17], (const float*)d_in[18],
      (const float*)d_in[19], (const float*)d_in[20], (const float*)d_in[21], (const float*)d_in[22],
      (const float*)d_in[23], (const float*)d_in[24], (const float*)d_in[25], (const float*)d_in[26],
      (const float*)d_in[27], (const float*)d_in[28], (const float*)d_in[29], (const float*)d_in[30],
      (float*)d_out);
  }
}